// Round 1
// baseline (143.894 us; speedup 1.0000x reference)
//
#include <hip/hip_runtime.h>
#include <hip/hip_cooperative_groups.h>

namespace cg = cooperative_groups;

typedef unsigned long long u64;

#define NIMG 4
#define H 256
#define W 256
#define NPIX (H*W)           // 65536 per image
#define NTOT (NIMG*NPIX)     // 262144
#define WPR 4                // u64 words per row (256 bits)
#define WPI (H*WPR)          // 1024 words per image
#define WPB (NIMG*WPI)       // 4096 words per branch
#define XT 16                // columns per edt tile block
#define NEDT 128             // edt/prep/sum blocks
#define NSKEL 8              // skeleton blocks (1 per branch-image)
#define NBLK (NEDT+NSKEL)    // 136 blocks, trivially co-resident on 256 CUs

// ---------------------------------------------------------------------------
// Bit-parallel morphology helpers. Bit b of word k = pixel x = 64k+b.
// Erode = AND over cross {c, up, down, left, right}, OOB treated as 1.
// Dilate = OR over 3x3 box, OOB treated as 0.
// ---------------------------------------------------------------------------
__device__ __forceinline__ void erode_from(const u64 S[][WPR], int y, u64 out[WPR]) {
  u64 c[WPR], up[WPR], dn[WPR];
#pragma unroll
  for (int k = 0; k < WPR; ++k) {
    c[k]  = S[y][k];
    up[k] = (y > 0)     ? S[y-1][k] : ~0ULL;
    dn[k] = (y < H-1)   ? S[y+1][k] : ~0ULL;
  }
#pragma unroll
  for (int k = 0; k < WPR; ++k) {
    u64 l = (c[k] << 1) | ((k > 0)     ? (c[k-1] >> 63) : 1ULL);
    u64 r = (c[k] >> 1) | ((k < WPR-1) ? (c[k+1] << 63) : 0x8000000000000000ULL);
    out[k] = c[k] & up[k] & dn[k] & l & r;
  }
}

__device__ __forceinline__ void dilate_from(const u64 S[][WPR], int y, u64 out[WPR]) {
  u64 v[WPR];
#pragma unroll
  for (int k = 0; k < WPR; ++k) {
    u64 a = S[y][k];
    if (y > 0)   a |= S[y-1][k];
    if (y < H-1) a |= S[y+1][k];
    v[k] = a;
  }
#pragma unroll
  for (int k = 0; k < WPR; ++k) {
    u64 l = (v[k] << 1) | ((k > 0)     ? (v[k-1] >> 63) : 0ULL);
    u64 r = (v[k] >> 1) | ((k < WPR-1) ? (v[k+1] << 63) : 0ULL);
    out[k] = v[k] | l | r;
  }
}

// ---------------------------------------------------------------------------
// Single cooperative kernel. 136 blocks x 256 threads.
//  P1  blocks 0..127 : pp = sigmoid(2*sigmoid(x)-1); ballot-pack yt & pp>0.5
//                      bitmasks. Block 0 re-inits rmm/sums/done counter.
//  --- grid.sync ---
//  P2  blocks 128..135: full 10-iter soft_skel in LDS (bit-packed), write
//                       skel_bits.                 [serial chain, 8 CUs]
//      blocks 0..127  : EDT distances (horizontal clz/ctz scan -> LDS col2,
//                       vertical early-exit envelope). Distances kept in
//                       REGISTERS across the sync; also stored to global edt.
//      (EDT needs only mask_bits -> skel hides under EDT instead of being a
//       serial kernel on the critical path.)
//  --- grid.sync ---
//  P3  blocks 0..127 : srad = skel_bit ? dist : 0 from register dists;
//                      block rmax/rmin reduce -> atomic merge into rmm_u.
//  --- grid.sync ---
//  P4  blocks 0..127 : per-pixel q terms (8 px/thread, float4 loads), block
//                      reduce, 4 double atomics. Last-done block (atomic
//                      counter + threadfence) computes the scalar loss.
// ---------------------------------------------------------------------------
__global__ void __launch_bounds__(256, 1) fused_kernel(
    const float* __restrict__ y_pred, const int* __restrict__ y_true,
    float* __restrict__ pp, u64* __restrict__ mask_bits, u64* __restrict__ skel_bits,
    float* __restrict__ edt, unsigned* __restrict__ rmm_u, double* __restrict__ sums,
    unsigned* __restrict__ done_cnt, float* __restrict__ out) {
  cg::grid_group grid = cg::this_grid();
  __shared__ u64 SA[H][WPR];
  __shared__ u64 SB[H][WPR];
  __shared__ float col2[H][XT + 1];   // pad 17: 2-way aliasing is free on gfx950
  __shared__ float redf[4][4];
  int t = threadIdx.x;

  // ---------------- P1: prep ----------------
  if (blockIdx.x < NEDT) {
    if (blockIdx.x == 0) {
      if (t < 16) rmm_u[t] = (t & 1) ? 0x7F800000u : 0u;   // min:+inf, max:0
      else if (t < 20) sums[t - 16] = 0.0;
      else if (t == 20) *done_cnt = 0u;
    }
    int g = blockIdx.x * 256 + t;
#pragma unroll
    for (int j = 0; j < 8; ++j) {
      int i = (j << 15) + g;          // wave's 64 lanes cover 64 consecutive px
      float x = y_pred[i];
      float p = 1.0f / (1.0f + expf(-x));
      float q = 1.0f / (1.0f + expf(-(2.0f * p - 1.0f)));
      pp[i] = q;
      u64 bt = __ballot(y_true[i] > 0);
      u64 bp = __ballot(q > 0.5f);
      if ((t & 63) == 0) {
        mask_bits[i >> 6] = bt;          // branch 0: true mask
        mask_bits[WPB + (i >> 6)] = bp;  // branch 1: pred hard mask (pp>0.5)
      }
    }
  }
  grid.sync();

  // ---------------- P2: skel || edt distances ----------------
  float dist_r[16];                      // live across grid.sync into P3
  if (blockIdx.x >= NEDT) {
    // --- soft_skel, bit-packed, 1 thread per row, ONE barrier per level ---
    int y = t;
    int base = (blockIdx.x - NEDT) * WPI;
    u64 a[WPR], cur[WPR], e[WPR], d[WPR], sk[WPR];
#pragma unroll
    for (int k = 0; k < WPR; ++k) { a[k] = mask_bits[base + y*WPR + k]; SA[y][k] = a[k]; }
    __syncthreads();
    erode_from(SA, y, e);                 // E1 = erode(a)
#pragma unroll
    for (int k = 0; k < WPR; ++k) SB[y][k] = e[k];
    __syncthreads();                      // SB visible; all SA reads complete
    dilate_from(SB, y, d);                // open(a)
#pragma unroll
    for (int k = 0; k < WPR; ++k) { sk[k] = a[k] & ~d[k]; cur[k] = e[k]; }
    u64 (*P)[WPR] = SB;                   // current erosion level E_k
    u64 (*Q)[WPR] = SA;                   // dead buffer
    for (int it = 0; it < 10; ++it) {     // levels 1..10
      erode_from(P, y, e);                // E_{k+1}
#pragma unroll
      for (int k = 0; k < WPR; ++k) Q[y][k] = e[k];   // overwrite dead data
      __syncthreads();                    // publish Q; P reads all done
      dilate_from(Q, y, d);               // open(E_k)
#pragma unroll
      for (int k = 0; k < WPR; ++k) { sk[k] |= cur[k] & ~d[k]; cur[k] = e[k]; }
      u64 (*T)[WPR] = P; P = Q; Q = T;
    }
#pragma unroll
    for (int k = 0; k < WPR; ++k) skel_bits[base + y*WPR + k] = sk[k];
  } else {
    // --- EDT distances for tile (bi, xt) --- needs only mask_bits
    int bi = blockIdx.x >> 4;            // 0..7 = branch*4+img
    int xt = blockIdx.x & 15;
    int x0 = xt * XT;
    int kx = x0 >> 6;                    // all tile columns in this u64 word
    // phase 1: thread = row y; horizontal EDT g via clz/ctz -> col2 = g^2
    {
      int y = t;
      const u64* row = mask_bits + bi*WPI + y*WPR;
      u64 z[WPR];
#pragma unroll
      for (int k = 0; k < WPR; ++k) z[k] = ~row[k];   // background bits
#pragma unroll
      for (int xx = 0; xx < XT; ++xx) {
        int x = x0 + xx;
        int bx = x & 63;
        int ld = 512;
        {
          u64 w = z[kx] & ((bx == 63) ? ~0ULL : ((1ULL << (bx+1)) - 1ULL));
          for (int k = kx; ; ) {
            if (w) { int pos = 63 - __builtin_clzll(w) + (k << 6); ld = x - pos; break; }
            if (--k < 0) break;
            w = z[k];
          }
        }
        int rd = 512;
        {
          u64 w = z[kx] & (~0ULL << bx);
          for (int k = kx; ; ) {
            if (w) { int pos = __builtin_ctzll(w) + (k << 6); rd = pos - x; break; }
            if (++k > WPR-1) break;
            w = z[k];
          }
        }
        int g = min(ld, rd);
        col2[y][xx] = (float)(g * g);
      }
    }
    __syncthreads();
    // phase 2: thread = (x in tile, ygrp of 16 rows); early-exit envelope
    int x  = t & (XT - 1);
    int yg = t >> 4;
#pragma unroll
    for (int j = 0; j < 16; ++j) {
      int y = yg * 16 + j;
      float best = col2[y][x];
      for (int k = 1; k < H; ++k) {
        float k2 = (float)(k * k);
        if (k2 >= best) break;           // no farther candidate can improve
        int ym = y - k, yq = y + k;
        if (ym >= 0) best = fminf(best, col2[ym][x] + k2);
        if (yq < H)  best = fminf(best, col2[yq][x] + k2);
      }
      float dist = sqrtf(best);
      dist_r[j] = dist;                  // keep in registers for P3
      edt[bi*NPIX + y*W + x0 + x] = dist;
    }
  }
  grid.sync();

  // ---------------- P3: srad + rmax/rmin ----------------
  if (blockIdx.x < NEDT) {
    int bi = blockIdx.x >> 4;
    int xt = blockIdx.x & 15;
    int x0 = xt * XT;
    int kx = x0 >> 6;
    int sh0 = x0 & 63;
    int x  = t & (XT - 1);
    int yg = t >> 4;
    float vmax = 0.0f, vmin = 3.0e38f;
#pragma unroll
    for (int j = 0; j < 16; ++j) {
      int y = yg * 16 + j;
      u64 sw = skel_bits[bi*WPI + y*WPR + kx];
      int sb = (int)((sw >> (sh0 + x)) & 1ULL);
      float srad = sb ? dist_r[j] : 0.0f; // == skel_radius for both branches
      vmax = fmaxf(vmax, srad);
      vmin = fminf(vmin, srad);
    }
    for (int o = 32; o > 0; o >>= 1) {
      vmax = fmaxf(vmax, __shfl_down(vmax, o, 64));
      vmin = fminf(vmin, __shfl_down(vmin, o, 64));
    }
    int wave = t >> 6, lane = t & 63;
    if (lane == 0) { redf[wave][0] = vmax; redf[wave][1] = vmin; }
    __syncthreads();
    if (t == 0) {
      float mx = redf[0][0], mn = redf[0][1];
      for (int wv = 1; wv < 4; ++wv) { mx = fmaxf(mx, redf[wv][0]); mn = fminf(mn, redf[wv][1]); }
      atomicMax(&rmm_u[bi*2 + 0], __float_as_uint(mx));
      atomicMin(&rmm_u[bi*2 + 1], __float_as_uint(mn));
    }
  }
  grid.sync();

  // ---------------- P4: q-term sums + tail finalize ----------------
  if (blockIdx.x < NEDT) {
    int g = blockIdx.x * 256 + t;
    int i0 = g * 8;                      // 8 px/thread, same u64 word
    int img = i0 >> 16;
    int wi  = i0 >> 6;
    int b0  = i0 & 63;                   // b0 <= 56: 8 bits in same word
    u64 mw_t = mask_bits[wi];
    u64 sw_t = skel_bits[wi];
    u64 sw_p = skel_bits[WPB + wi];
    float4 dt0 = *(const float4*)(edt + i0);
    float4 dt1 = *(const float4*)(edt + i0 + 4);
    float4 dp0 = *(const float4*)(edt + NTOT + i0);
    float4 dp1 = *(const float4*)(edt + NTOT + i0 + 4);
    float4 pq0 = *(const float4*)(pp + i0);
    float4 pq1 = *(const float4*)(pp + i0 + 4);
    float rmax_t = fmaxf(__uint_as_float(rmm_u[img*2 + 0]), 1.0f);
    float rmin_t = fmaxf(__uint_as_float(rmm_u[img*2 + 1]), 1.0f);
    float rmax_p = fmaxf(__uint_as_float(rmm_u[(4+img)*2 + 0]), 1.0f);
    float rmin_p = fmaxf(__uint_as_float(rmm_u[(4+img)*2 + 1]), 1.0f);
    float dts[8] = {dt0.x,dt0.y,dt0.z,dt0.w,dt1.x,dt1.y,dt1.z,dt1.w};
    float dps[8] = {dp0.x,dp0.y,dp0.z,dp0.w,dp1.x,dp1.y,dp1.z,dp1.w};
    float pps[8] = {pq0.x,pq0.y,pq0.z,pq0.w,pq1.x,pq1.y,pq1.z,pq1.w};
    float q1 = 0.f, q2 = 0.f, q3 = 0.f, q4 = 0.f;
#pragma unroll
    for (int j = 0; j < 8; ++j) {
      int b = b0 + j;
      // --- true branch (binary) ---
      int m_t = (int)((mw_t >> b) & 1ULL);
      int s_t = (int)((sw_t >> b) & 1ULL);
      float distances_t = m_t ? dts[j] : 0.0f;
      float skelrad_t   = s_t ? distances_t : 0.0f;
      float dmn_t = fminf(distances_t, rmax_t) / rmax_t;
      float srn_t = skelrad_t / rmax_t;
      float In_t  = s_t ? (rmax_t - skelrad_t + rmin_t) / rmax_t : 0.0f;
      float q_vl   = m_t ? dmn_t : 0.0f;
      float q_slvl = m_t ? srn_t : 0.0f;
      float q_sl   = s_t ? In_t  : 0.0f;
      // --- pred branch (probabilistic) ---
      int s_pb = (int)((sw_p >> b) & 1ULL);
      float ppv = pps[j];
      float skel_in_p = s_pb ? ppv : 0.0f;      // skel_pred_prob
      bool msk_p = ppv > 0.5f;
      bool sk_p  = skel_in_p > 0.5f;
      float distances_p = msk_p ? dps[j] : 0.0f;
      float skelrad_p   = sk_p ? distances_p : 0.0f;
      float dmn_p = fminf(distances_p, rmax_p) / rmax_p;
      float srn_p = skelrad_p / rmax_p;
      float In_p  = sk_p ? (rmax_p - skelrad_p + rmin_p) / rmax_p : 0.0f;
      float q_vp   = dmn_p * ppv;
      float q_spvp = srn_p * ppv;
      float q_sp   = In_p * skel_in_p;
      q1 += q_sp * q_vl;
      q2 += (q_spvp != 0.0f && q_slvl == 0.0f) ? q_spvp * q_sp : q_slvl * q_sp;
      q3 += q_sl * q_vp;
      q4 += (q_slvl != 0.0f && q_spvp == 0.0f) ? q_slvl * q_sl : q_spvp * q_sl;
    }
    for (int o = 32; o > 0; o >>= 1) {
      q1 += __shfl_down(q1, o, 64);
      q2 += __shfl_down(q2, o, 64);
      q3 += __shfl_down(q3, o, 64);
      q4 += __shfl_down(q4, o, 64);
    }
    int wave = t >> 6, lane = t & 63;
    if (lane == 0) { redf[wave][0]=q1; redf[wave][1]=q2; redf[wave][2]=q3; redf[wave][3]=q4; }
    __syncthreads();
    if (t == 0) {
      float a0=0,a1=0,a2=0,a3=0;
      for (int wv = 0; wv < 4; ++wv) {
        a0 += redf[wv][0]; a1 += redf[wv][1]; a2 += redf[wv][2]; a3 += redf[wv][3];
      }
      atomicAdd(&sums[0], (double)a0);
      atomicAdd(&sums[1], (double)a1);
      atomicAdd(&sums[2], (double)a2);
      atomicAdd(&sums[3], (double)a3);
      __threadfence();                    // publish sums before counting done
      unsigned c = atomicAdd(done_cnt, 1u);
      if (c == NEDT - 1) {                // last block finalizes (device-scope
        double s0 = atomicAdd(&sums[0], 0.0);   // atomic loads for coherence)
        double s1 = atomicAdd(&sums[1], 0.0);
        double s2 = atomicAdd(&sums[2], 0.0);
        double s3 = atomicAdd(&sums[3], 0.0);
        double wp  = (s0 + 1.0) / (s1 + 1.0);
        double wsn = (s2 + 1.0) / (s3 + 1.0);
        out[0] = (float)(1.0 - 2.0 * (wp * wsn) / (wp + wsn));
      }
    }
  }
}

extern "C" void kernel_launch(void* const* d_in, const int* in_sizes, int n_in,
                              void* d_out, int out_size, void* d_ws, size_t ws_size,
                              hipStream_t stream) {
  (void)in_sizes; (void)n_in; (void)out_size; (void)ws_size;
  const float* y_pred = (const float*)d_in[0];
  const int*   y_true = (const int*)d_in[1];
  float* out = (float*)d_out;
  char* ws = (char*)d_ws;

  // workspace layout (bytes)
  float* pp        = (float*)(ws + 0);          // 262144 f  (1,048,576 B)
  float* edt       = (float*)(ws + 1048576);    // 524288 f  (2,097,152 B) [branch][img][y][x]
  u64*   mask_bits = (u64*)  (ws + 3145728);    // 8192 u64  (65,536 B)
  u64*   skel_bits = (u64*)  (ws + 3211264);    // 8192 u64  (65,536 B)
  unsigned* rmm_u  = (unsigned*)(ws + 3276800); // 16 u32
  double* sums     = (double*)(ws + 3276864);   // 4 d
  unsigned* done_cnt = (unsigned*)(ws + 3276896); // 1 u32

  void* args[] = { (void*)&y_pred, (void*)&y_true, (void*)&pp, (void*)&mask_bits,
                   (void*)&skel_bits, (void*)&edt, (void*)&rmm_u, (void*)&sums,
                   (void*)&done_cnt, (void*)&out };
  hipLaunchCooperativeKernel((void*)fused_kernel, dim3(NBLK), dim3(256),
                             args, 0, stream);
}